// Round 2
// baseline (4433.844 us; speedup 1.0000x reference)
//
#include <hip/hip_runtime.h>

// ---------------------------------------------------------------------------
// Performer-style linear attention, fp32 baseline.
// Layout convention: all activation tensors are token-major [B*N, 1024],
// head h occupying columns h*64 .. h*64+63 (matches reference reshape).
// ---------------------------------------------------------------------------

#define ROWS_TOT 32768   // B*N = 4*8192
#define DMODEL   1024
#define NHEADS   16
#define DK       64      // head dim == feature count F

// ===========================================================================
// GEMM: C[M,N] = A[M,K] * Bw[N,K]^T + bias[N]
// A row-major, Bw row-major (so both operands are K-contiguous).
// 128x128 tile, BK=16, 256 threads, 8x8 micro-tile (split 4+4 strides).
// ===========================================================================
__global__ __launch_bounds__(256) void sgemm_bt(
    const float* __restrict__ A, const float* __restrict__ Bw,
    const float* __restrict__ bias, float* __restrict__ C,
    int M, int N, int K)
{
    __shared__ float As[16][132];
    __shared__ float Bs[16][132];
    const int t  = threadIdx.x;
    const int m0 = blockIdx.y * 128;
    const int n0 = blockIdx.x * 128;

    // cooperative load indices: 64 rows x 16 k per tensor, 2 rows/thread
    const int lr = t >> 2;          // 0..63
    const int lk = (t & 3) << 2;    // 0,4,8,12

    const float* ap0 = A  + (long)(m0 + lr) * K + lk;
    const float* ap1 = ap0 + (long)64 * K;
    const float* bp0 = Bw + (long)(n0 + lr) * K + lk;
    const float* bp1 = bp0 + (long)64 * K;

    const int tx = t & 15;          // column group
    const int ty = t >> 4;          // row group

    float acc[8][8];
#pragma unroll
    for (int i = 0; i < 8; ++i)
#pragma unroll
        for (int j = 0; j < 8; ++j) acc[i][j] = 0.f;

    for (int kt = 0; kt < K; kt += 16) {
        float4 a0 = *(const float4*)ap0;
        float4 a1 = *(const float4*)ap1;
        float4 b0 = *(const float4*)bp0;
        float4 b1 = *(const float4*)bp1;
        ap0 += 16; ap1 += 16; bp0 += 16; bp1 += 16;

        __syncthreads();   // previous tile's compute done before overwrite
        As[lk+0][lr]    = a0.x; As[lk+1][lr]    = a0.y;
        As[lk+2][lr]    = a0.z; As[lk+3][lr]    = a0.w;
        As[lk+0][64+lr] = a1.x; As[lk+1][64+lr] = a1.y;
        As[lk+2][64+lr] = a1.z; As[lk+3][64+lr] = a1.w;
        Bs[lk+0][lr]    = b0.x; Bs[lk+1][lr]    = b0.y;
        Bs[lk+2][lr]    = b0.z; Bs[lk+3][lr]    = b0.w;
        Bs[lk+0][64+lr] = b1.x; Bs[lk+1][64+lr] = b1.y;
        Bs[lk+2][64+lr] = b1.z; Bs[lk+3][64+lr] = b1.w;
        __syncthreads();

#pragma unroll
        for (int kk = 0; kk < 16; ++kk) {
            float4 xa0 = *(const float4*)&As[kk][ty*4];
            float4 xa1 = *(const float4*)&As[kk][64 + ty*4];
            float4 xb0 = *(const float4*)&Bs[kk][tx*4];
            float4 xb1 = *(const float4*)&Bs[kk][64 + tx*4];
            float a[8] = {xa0.x,xa0.y,xa0.z,xa0.w, xa1.x,xa1.y,xa1.z,xa1.w};
            float b[8] = {xb0.x,xb0.y,xb0.z,xb0.w, xb1.x,xb1.y,xb1.z,xb1.w};
#pragma unroll
            for (int i = 0; i < 8; ++i)
#pragma unroll
                for (int j = 0; j < 8; ++j)
                    acc[i][j] += a[i] * b[j];
        }
    }

    const float4 bv0 = *(const float4*)&bias[n0 + tx*4];
    const float4 bv1 = *(const float4*)&bias[n0 + 64 + tx*4];
    const float bb[8] = {bv0.x,bv0.y,bv0.z,bv0.w, bv1.x,bv1.y,bv1.z,bv1.w};
#pragma unroll
    for (int i = 0; i < 8; ++i) {
        int row = m0 + ((i < 4) ? (ty*4 + i) : (64 + ty*4 + i - 4));
        float4 o0 = make_float4(acc[i][0]+bb[0], acc[i][1]+bb[1],
                                acc[i][2]+bb[2], acc[i][3]+bb[3]);
        float4 o1 = make_float4(acc[i][4]+bb[4], acc[i][5]+bb[5],
                                acc[i][6]+bb[6], acc[i][7]+bb[7]);
        *(float4*)&C[(long)row * N + n0 + tx*4]      = o0;
        *(float4*)&C[(long)row * N + n0 + 64 + tx*4] = o1;
    }
}

// ===========================================================================
// Feature map, in place: for each (token,head) 64-chunk y:
//   y[f] = relu(norm * dot(y, P[f,:])) + 1e-6
// One wave per chunk; lane l = output feature l; P row held in 16 float4 regs.
// Row is read via wave-uniform float4 loads (broadcast), then overwritten —
// safe: loads feed the FMA chain before the store (data dependency).
// ===========================================================================
__global__ __launch_bounds__(256) void feat_kernel(
    float* __restrict__ Y, const float* __restrict__ P, int nrows)
{
    const int l = threadIdx.x & 63;
    const int w = threadIdx.x >> 6;

    float4 p[16];
#pragma unroll
    for (int i = 0; i < 16; ++i)
        p[i] = *(const float4*)&P[l*64 + i*4];

    const float norm = 0.35355339059327373f;   // 64^(-1/4)

    for (int r = blockIdx.x*4 + w; r < nrows; r += gridDim.x*4) {
        const float4* y4 = (const float4*)(Y + (long)r * 64);
        float acc = 0.f;
#pragma unroll
        for (int i = 0; i < 16; ++i) {
            float4 yv = y4[i];
            acc += yv.x*p[i].x + yv.y*p[i].y + yv.z*p[i].z + yv.w*p[i].w;
        }
        acc *= norm;
        acc = (acc > 0.f ? acc : 0.f) + 1e-6f;
        Y[(long)r * 64 + l] = acc;
    }
}

// ===========================================================================
// KV reduction: per (b,h): KV[f,d] = sum_n Kf[n,f]*V[n,d]; Ksum[f] = sum_n Kf.
// Grid = 64 pairs x 32 chunks (256 tokens each). Block 256 threads:
// thread owns a 4f x 4d register tile; one atomicAdd per output per block.
// ===========================================================================
__global__ __launch_bounds__(256) void kv_reduce(
    const float* __restrict__ KF, const float* __restrict__ V,
    float* __restrict__ KVg, float* __restrict__ KSg)
{
    const int t  = threadIdx.x;
    const int fq = t & 15;          // f quad: features fq*4..fq*4+3
    const int dg = t >> 4;          // d quad: dims dg*4..dg*4+3 (0..15)
    const int p  = blockIdx.x >> 5; // pair 0..63  (b*16+h)
    const int ch = blockIdx.x & 31; // token chunk
    const int b  = p >> 4, h = p & 15;

    float acc[4][4];
#pragma unroll
    for (int i = 0; i < 4; ++i)
#pragma unroll
        for (int j = 0; j < 4; ++j) acc[i][j] = 0.f;
    float ksum[4] = {0.f, 0.f, 0.f, 0.f};

    const long base = ((long)b * 8192 + (long)ch * 256) * DMODEL + h * 64;
    for (int n = 0; n < 256; ++n) {
        const float4 kf = *(const float4*)(KF + base + (long)n * DMODEL + fq*4);
        const float4 vv = *(const float4*)(V  + base + (long)n * DMODEL + dg*4);
        acc[0][0] += kf.x*vv.x; acc[0][1] += kf.x*vv.y; acc[0][2] += kf.x*vv.z; acc[0][3] += kf.x*vv.w;
        acc[1][0] += kf.y*vv.x; acc[1][1] += kf.y*vv.y; acc[1][2] += kf.y*vv.z; acc[1][3] += kf.y*vv.w;
        acc[2][0] += kf.z*vv.x; acc[2][1] += kf.z*vv.y; acc[2][2] += kf.z*vv.z; acc[2][3] += kf.z*vv.w;
        acc[3][0] += kf.w*vv.x; acc[3][1] += kf.w*vv.y; acc[3][2] += kf.w*vv.z; acc[3][3] += kf.w*vv.w;
        ksum[0] += kf.x; ksum[1] += kf.y; ksum[2] += kf.z; ksum[3] += kf.w;
    }

    float* kvp = KVg + p * (DK*DK);
#pragma unroll
    for (int i = 0; i < 4; ++i)
#pragma unroll
        for (int j = 0; j < 4; ++j)
            atomicAdd(&kvp[(fq*4 + i) * DK + dg*4 + j], acc[i][j]);
    if (dg == 0) {
#pragma unroll
        for (int i = 0; i < 4; ++i)
            atomicAdd(&KSg[p * DK + fq*4 + i], ksum[i]);
    }
}

// ===========================================================================
// Attention readout, in place over Qf:
//   out[d] = (sum_f Qf[f]*KV[f,d]) / (sum_f Qf[f]*Ksum[f] + 1e-6)
// One wave per token; lane d holds KV column d (64 regs) + Ksum (64 regs).
// Grid = 64 pairs x 16 chunks (512 tokens each).
// ===========================================================================
__global__ __launch_bounds__(256) void attn_kernel(
    float* __restrict__ QF, const float* __restrict__ KVg,
    const float* __restrict__ KSg)
{
    const int l  = threadIdx.x & 63;   // output dim d
    const int w  = threadIdx.x >> 6;
    const int p  = blockIdx.x >> 4;    // pair
    const int ch = blockIdx.x & 15;    // token chunk (512)
    const int b  = p >> 4, h = p & 15;

    float kv[64];
    float ks[64];
#pragma unroll
    for (int f = 0; f < 64; ++f) kv[f] = KVg[p*(DK*DK) + f*DK + l];
#pragma unroll
    for (int f = 0; f < 64; ++f) ks[f] = KSg[p*DK + f];

    const long rowbase = (long)b * 8192;
    for (int i = 0; i < 128; ++i) {
        const int  tok = ch*512 + i*4 + w;
        const long row = rowbase + tok;
        const float4* q4 = (const float4*)(QF + row * DMODEL + h * 64);
        float acc = 0.f, den = 0.f;
#pragma unroll
        for (int fi = 0; fi < 16; ++fi) {
            float4 qv = q4[fi];
            acc += qv.x*kv[fi*4+0] + qv.y*kv[fi*4+1] + qv.z*kv[fi*4+2] + qv.w*kv[fi*4+3];
            den += qv.x*ks[fi*4+0] + qv.y*ks[fi*4+1] + qv.z*ks[fi*4+2] + qv.w*ks[fi*4+3];
        }
        const float out = acc / (den + 1e-6f);
        QF[row * DMODEL + h * 64 + l] = out;   // loads consumed before store
    }
}

// ===========================================================================
extern "C" void kernel_launch(void* const* d_in, const int* in_sizes, int n_in,
                              void* d_out, int out_size, void* d_ws, size_t ws_size,
                              hipStream_t stream)
{
    const float* x  = (const float*)d_in[0];
    const float* Wq = (const float*)d_in[1];
    const float* bq = (const float*)d_in[2];
    const float* Wk = (const float*)d_in[3];
    const float* bk = (const float*)d_in[4];
    const float* Wv = (const float*)d_in[5];
    const float* bv = (const float*)d_in[6];
    const float* Wo = (const float*)d_in[7];
    const float* bo = (const float*)d_in[8];
    const float* P  = (const float*)d_in[9];
    float* out = (float*)d_out;

    const size_t TEN = (size_t)ROWS_TOT * DMODEL * sizeof(float); // 128 MiB
    char* ws = (char*)d_ws;
    float* Q  = (float*)(ws);             // -> Qf -> attn out (in place)
    float* Kb = (float*)(ws + TEN);       // -> Kf (in place)
    float* Vb = (float*)(ws + 2*TEN);
    float* KV = (float*)(ws + 3*TEN);                         // 64*64*64 f32
    float* KS = (float*)(ws + 3*TEN + 64*64*64*sizeof(float)); // 64*64 f32
    if (ws_size < 3*TEN + (64*64*64 + 64*64) * sizeof(float)) return;

    dim3 gg(DMODEL/128, ROWS_TOT/128), bb(256);
    sgemm_bt<<<gg, bb, 0, stream>>>(x, Wq, bq, Q,  ROWS_TOT, DMODEL, DMODEL);
    sgemm_bt<<<gg, bb, 0, stream>>>(x, Wk, bk, Kb, ROWS_TOT, DMODEL, DMODEL);
    sgemm_bt<<<gg, bb, 0, stream>>>(x, Wv, bv, Vb, ROWS_TOT, DMODEL, DMODEL);

    feat_kernel<<<2048, 256, 0, stream>>>(Q,  P, ROWS_TOT * NHEADS);
    feat_kernel<<<2048, 256, 0, stream>>>(Kb, P, ROWS_TOT * NHEADS);

    hipMemsetAsync(KV, 0, (64*64*64 + 64*64) * sizeof(float), stream);
    kv_reduce<<<2048, 256, 0, stream>>>(Kb, Vb, KV, KS);
    attn_kernel<<<1024, 256, 0, stream>>>(Q, KV, KS);

    sgemm_bt<<<gg, bb, 0, stream>>>(Q, Wo, bo, out, ROWS_TOT, DMODEL, DMODEL);
}